// Round 1
// baseline (165.071 us; speedup 1.0000x reference)
//
#include <hip/hip_runtime.h>
#include <math.h>

#define HW 4096          // 64*64
#define NB 8
#define NC 512
#define NCHUNK 8
#define CPERCHUNK 64     // 512/8

// ---------------------------------------------------------------------------
// Kernel 1: partial 1x1 convs over a 64-channel chunk.
// part layout: part[(chunk*2 + tensor)*32768 + b*4096 + hw]   (tensor 0=fm,1=x)
// grid: (hw_tile=4, chunk=8, b=8), block=256, each thread does 4 pixels (float4)
// ---------------------------------------------------------------------------
__global__ __launch_bounds__(256) void conv_partial(
    const float* __restrict__ fm, const float* __restrict__ x,
    const float* __restrict__ w1, const float* __restrict__ w2,
    float* __restrict__ part)
{
    const int t     = threadIdx.x;
    const int hw4   = blockIdx.x * 1024 + t * 4;   // 4 consecutive pixels
    const int chunk = blockIdx.y;
    const int b     = blockIdx.z;
    const int c0    = chunk * CPERCHUNK;

    const float* fmb = fm + ((size_t)b * NC + c0) * HW + hw4;
    const float* xb  = x  + ((size_t)b * NC + c0) * HW + hw4;

    float af0 = 0.f, af1 = 0.f, af2 = 0.f, af3 = 0.f;
    float ax0 = 0.f, ax1 = 0.f, ax2 = 0.f, ax3 = 0.f;

    #pragma unroll 4
    for (int cc = 0; cc < CPERCHUNK; ++cc) {
        float4 f = *(const float4*)(fmb + (size_t)cc * HW);
        float4 g = *(const float4*)(xb  + (size_t)cc * HW);
        float wa = w1[c0 + cc];
        float wb = w2[c0 + cc];
        af0 = fmaf(f.x, wa, af0); af1 = fmaf(f.y, wa, af1);
        af2 = fmaf(f.z, wa, af2); af3 = fmaf(f.w, wa, af3);
        ax0 = fmaf(g.x, wb, ax0); ax1 = fmaf(g.y, wb, ax1);
        ax2 = fmaf(g.z, wb, ax2); ax3 = fmaf(g.w, wb, ax3);
    }

    float* pf = part + ((size_t)(chunk * 2 + 0) * NB + b) * HW + hw4;
    float* px = part + ((size_t)(chunk * 2 + 1) * NB + b) * HW + hw4;
    *(float4*)pf = make_float4(af0, af1, af2, af3);
    *(float4*)px = make_float4(ax0, ax1, ax2, ax3);
}

// ---------------------------------------------------------------------------
// Kernel 2: sum the 8 chunk partials, add bias, ReLU.
// i = tensor*32768 + b*4096 + hw ; 65536 threads total.
// ---------------------------------------------------------------------------
__global__ __launch_bounds__(256) void reduce_bias_relu(
    const float* __restrict__ part,
    const float* __restrict__ b1, const float* __restrict__ b2,
    float* __restrict__ recon, float* __restrict__ refmap)
{
    const int i      = blockIdx.x * 256 + threadIdx.x;   // 0..65535
    const int tensor = i >> 15;                           // 0 or 1
    const int bhw    = i & 32767;

    float s = 0.f;
    #pragma unroll
    for (int ch = 0; ch < NCHUNK; ++ch)
        s += part[(size_t)(ch * 2 + tensor) * 32768 + bhw];

    const float bias = (tensor == 0) ? b1[0] : b2[0];
    const float r = fmaxf(s + bias, 0.f);
    if (tensor == 0) recon[bhw]  = r;
    else             refmap[bhw] = r;
}

// ---------------------------------------------------------------------------
// Kernel 3: correlation argmax + gather + fold.
// One wave per patch; 4 waves (4 patches) per block; 2048 blocks = 8 b * 256.
// gg in LDS: 65x65 zero-padded recon, stride 65 (bank = (p+q)%32, conflict-free).
// ---------------------------------------------------------------------------
__global__ __launch_bounds__(256) void correlate_gather(
    const float* __restrict__ recon, const float* __restrict__ refmap,
    float* __restrict__ out)
{
    __shared__ float gg[65 * 65];

    const int b     = blockIdx.x >> 8;          // 256 blocks per batch
    const int pbase = (blockIdx.x & 255) * 4;   // 4 patches per block
    const int t     = threadIdx.x;

    // stage zero-padded recon for this batch into LDS
    const float* rb = recon + (size_t)b * HW;
    for (int i = t; i < 65 * 65; i += 256) {
        const int r = i / 65;
        const int c = i - r * 65;
        gg[i] = (r < 64 && c < 64) ? rb[r * 64 + c] : 0.f;
    }
    __syncthreads();

    const int wave = t >> 6;
    const int lane = t & 63;
    const int l    = pbase + wave;       // patch index in [0,1024)
    const int ph   = l >> 5;
    const int pw   = l & 31;

    // 2x2 kernel from refmap patch l (wave-uniform addresses)
    const float* km = refmap + (size_t)b * HW + (ph * 2) * 64 + pw * 2;
    const float k00 = km[0], k01 = km[1], k10 = km[64], k11 = km[65];

    // lane handles window row p = lane; slide over q, reusing right->left
    const int p = lane;
    const float* row0 = gg + p * 65;
    const float* row1 = row0 + 65;

    float best = -INFINITY;
    int   bpos = 0;
    float a  = row0[0];
    float cv = row1[0];
    #pragma unroll
    for (int q = 0; q < 64; ++q) {
        const float bv = row0[q + 1];
        const float dv = row1[q + 1];
        // term order matches einsum reduction order (c, di, dj)
        float v = k00 * a;
        v = fmaf(k01, bv, v);
        v = fmaf(k10, cv, v);
        v = fmaf(k11, dv, v);
        const int pos = p * 64 + q;
        if (v > best) { best = v; bpos = pos; }   // strict > = first-max-wins within lane
        a  = bv;
        cv = dv;
    }

    // butterfly reduce across 64 lanes: max value, min position on ties
    #pragma unroll
    for (int m = 1; m < 64; m <<= 1) {
        const float ov = __shfl_xor(best, m, 64);
        const int   op = __shfl_xor(bpos, m, 64);
        if (ov > best || (ov == best && op < bpos)) { best = ov; bpos = op; }
    }

    if (lane == 0) {
        const int idx = bpos >> 2;       // offset // 4
        const int ph2 = idx >> 5;
        const int pw2 = idx & 31;
        const float* src = gg + (ph2 * 2) * 65 + pw2 * 2;   // recon patch idx
        float* o = out + (size_t)b * HW + (ph * 2) * 64 + pw * 2;
        o[0]  = src[0];
        o[1]  = src[1];
        o[64] = src[65];
        o[65] = src[66];
    }
}

// ---------------------------------------------------------------------------
extern "C" void kernel_launch(void* const* d_in, const int* in_sizes, int n_in,
                              void* d_out, int out_size, void* d_ws, size_t ws_size,
                              hipStream_t stream)
{
    const float* spade_fm = (const float*)d_in[0];
    const float* x        = (const float*)d_in[1];
    const float* w1       = (const float*)d_in[2];
    const float* b1       = (const float*)d_in[3];
    const float* w2       = (const float*)d_in[4];
    const float* b2       = (const float*)d_in[5];
    float* out = (float*)d_out;

    float* part   = (float*)d_ws;                 // 16 * 32768 floats = 2 MB
    float* recon  = part + 16 * 32768;            // 8*4096 floats
    float* refmap = recon + NB * HW;              // 8*4096 floats

    dim3 g1(4, NCHUNK, NB);
    conv_partial<<<g1, 256, 0, stream>>>(spade_fm, x, w1, w2, part);
    reduce_bias_relu<<<256, 256, 0, stream>>>(part, b1, b2, recon, refmap);
    correlate_gather<<<2048, 256, 0, stream>>>(recon, refmap, out);
}